// Round 11
// baseline (287.754 us; speedup 1.0000x reference)
//
#include <hip/hip_runtime.h>
#include <hip/hip_bf16.h>
#include <math.h>

typedef __hip_bfloat16 bf16;
typedef __attribute__((ext_vector_type(8))) short short8v;
typedef __attribute__((ext_vector_type(4))) float float4v;
typedef __attribute__((ext_vector_type(2))) float float2v;

__device__ __forceinline__ float b2f(bf16 v) { return __bfloat162float(v); }
__device__ __forceinline__ float bs2f(unsigned short s) {
    unsigned u = ((unsigned)s) << 16;
    float f; __builtin_memcpy(&f, &u, 4); return f;
}
__device__ __forceinline__ float ubits(unsigned u) {
    float f; __builtin_memcpy(&f, &u, 4); return f;
}
__device__ __forceinline__ short f2bs(float v) {
    bf16 b = __float2bfloat16(v);
    short s; __builtin_memcpy(&s, &b, 2); return s;
}
__device__ __forceinline__ float lrelu(float v) { return fmaxf(v, 0.2f * v); }
__device__ __forceinline__ float ldf(const void* p, size_t i, int bf) {
    return bf ? b2f(((const bf16*)p)[i]) : ((const float*)p)[i];
}
__device__ __forceinline__ int ld_src(const int* ei, int e, int E, int f64, int N) {
    int v = f64 ? (int)(((const long long*)ei)[e]) : ei[e];
    if ((unsigned)v >= (unsigned)N) v = 0;
    return v;
}
__device__ __forceinline__ int ld_dst(const int* ei, int e, int E, int f64, int N) {
    int v = f64 ? (int)(((const long long*)ei)[(size_t)E + e]) : ei[(size_t)E + e];
    if ((unsigned)v >= (unsigned)N) v = 0;
    return v;
}

#define EPB 4096   // edges per block in binning passes
#define SB  8      // bucket shift: 256 nodes per bucket

// ---------------------------------------------------------------------------
// K0: dtype detection + bcnt zeroing. flags[0]=int64 edges, flags[1]=bf16.
// ---------------------------------------------------------------------------
__global__ void k_detect(const int* __restrict__ ei, const unsigned* __restrict__ xw,
                         int* __restrict__ flags, int* __restrict__ bcnt, int nbuck)
{
    __shared__ int s_or[256];
    __shared__ int s_cnt[256];
    int t = threadIdx.x;
    for (int j = t; j < nbuck; j += 256) bcnt[j] = 0;
    int any = 0, cnt = 0;
    for (int i = t; i < 4096; i += 256) {
        any |= ei[2 * i + 1];
        unsigned e = (xw[i] >> 7) & 0xFFu;
        cnt += (e >= 100u && e <= 134u) ? 1 : 0;
    }
    s_or[t] = any; s_cnt[t] = cnt;
    __syncthreads();
    for (int s = 128; s > 0; s >>= 1) {
        if (t < s) { s_or[t] |= s_or[t + s]; s_cnt[t] += s_cnt[t + s]; }
        __syncthreads();
    }
    if (t == 0) {
        flags[0] = (s_or[0] == 0) ? 1 : 0;
        flags[1] = (s_cnt[0] > 2048) ? 1 : 0;
    }
}

// ---------------------------------------------------------------------------
// K1 combo: blocks [0,ebl) = bucket histogram; blocks [ebl,ebl+64) = W1->frag.
// ---------------------------------------------------------------------------
__global__ void __launch_bounds__(256)
k_prep(const int* __restrict__ ei, const void* __restrict__ W1,
       const int* __restrict__ flags, int* __restrict__ bcnt,
       short* __restrict__ w1frag, int E, int N, int nbuck, int ebl)
{
    int t = threadIdx.x;
    if (blockIdx.x >= ebl) {
        int bf = flags[1];
        int idx = (blockIdx.x - ebl) * 256 + t;
        if (idx < 16384) {
            int j = idx & 7, l = (idx >> 3) & 63, kk = (idx >> 9) & 3, ct = idx >> 11;
            int k = kk * 32 + (l >> 4) * 8 + j;
            int n = ct * 16 + (l & 15);
            w1frag[idx] = bf ? ((const short*)W1)[k * 128 + n]
                             : f2bs(((const float*)W1)[k * 128 + n]);
        }
        return;
    }
    __shared__ int hist[512];
    for (int j = t; j < nbuck; j += 256) hist[j] = 0;
    __syncthreads();
    int f = flags[0];
    int beg = blockIdx.x * EPB, end = min(E, beg + EPB);
    for (int i = beg + t; i < end; i += 256)
        atomicAdd(&hist[ld_dst(ei, i, E, f, N) >> SB], 1);
    __syncthreads();
    for (int j = t; j < nbuck; j += 256)
        if (hist[j]) atomicAdd(&bcnt[j], hist[j]);
}

// ---------------------------------------------------------------------------
// K2 combo: block 0 = bucket scan; blocks >=1 = MFMA GEMM + fused a_s/a_d.
// ---------------------------------------------------------------------------
#define GP 136   // LDS row pitch in shorts

__global__ void __launch_bounds__(256)
k_gemm_scan(const void* __restrict__ x, const short* __restrict__ w1frag,
            const void* __restrict__ att_src, const void* __restrict__ att_dst,
            const int* __restrict__ flags, bf16* __restrict__ h1b,
            float* __restrict__ a_s, float* __restrict__ a_d,
            const int* __restrict__ bcnt, int* __restrict__ bofs,
            int* __restrict__ bcur, int* __restrict__ offsets,
            int N, int E, int nbuck)
{
    int t = threadIdx.x;
    if (blockIdx.x == 0) {     // ---- bucket scan ----
        __shared__ int ps[256];
        int i0 = 2 * t, i1 = 2 * t + 1;
        int c0 = (i0 < nbuck) ? bcnt[i0] : 0;
        int c1 = (i1 < nbuck) ? bcnt[i1] : 0;
        int pr = c0 + c1;
        ps[t] = pr;
        __syncthreads();
        for (int s = 1; s < 256; s <<= 1) {
            int add = (t >= s) ? ps[t - s] : 0;
            __syncthreads();
            ps[t] += add;
            __syncthreads();
        }
        int excl = ps[t] - pr;
        if (i0 < nbuck) { bofs[i0] = excl; bcur[i0] = excl; }
        if (i1 < nbuck) { bofs[i1] = excl + c0; bcur[i1] = excl + c0; }
        if (t == 0) { bofs[nbuck] = E; offsets[N] = E; }
        return;
    }
    // ---- GEMM ----
    __shared__ short xs[64 * GP];
    int bf = flags[1];
    int blk = blockIdx.x - 1;
    int base = blk * 64;
    if (bf) {
        const short8v* xp = (const short8v*)x;
        for (int idx = t; idx < 1024; idx += 256) {
            int m = idx >> 4, v8 = idx & 15;
            int gm = base + m;
            short8v v = (gm < N) ? xp[(size_t)gm * 16 + v8]
                                 : (short8v){0,0,0,0,0,0,0,0};
            *(short8v*)&xs[m * GP + v8 * 8] = v;
        }
    } else {
        const float4* xp = (const float4*)x;
        for (int idx = t; idx < 2048; idx += 256) {
            int m = idx >> 5, v4 = idx & 31;
            int gm = base + m;
            float4 f = (gm < N) ? xp[(size_t)gm * 32 + v4]
                                : make_float4(0.f, 0.f, 0.f, 0.f);
            short* d = &xs[m * GP + v4 * 4];
            d[0] = f2bs(f.x); d[1] = f2bs(f.y); d[2] = f2bs(f.z); d[3] = f2bs(f.w);
        }
    }
    __syncthreads();

    int wv = t >> 6, l = t & 63, lq = l >> 4, lr = l & 15;
    int m0 = base + wv * 16;

    short8v afr[4];
#pragma unroll
    for (int kk = 0; kk < 4; ++kk)
        afr[kk] = *(const short8v*)&xs[(wv * 16 + lr) * GP + kk * 32 + lq * 8];

    float4v acc[8];
#pragma unroll
    for (int ct = 0; ct < 8; ++ct) acc[ct] = (float4v){0.f, 0.f, 0.f, 0.f};

#pragma unroll
    for (int kk = 0; kk < 4; ++kk) {
        short8v a = afr[kk];
#pragma unroll
        for (int ct = 0; ct < 8; ++ct) {
            short8v b = *(const short8v*)(w1frag + (((ct * 4 + kk) * 64 + l) << 3));
            acc[ct] = __builtin_amdgcn_mfma_f32_16x16x32_bf16(a, b, acc[ct], 0, 0, 0);
        }
    }
    __syncthreads();

#pragma unroll
    for (int ct = 0; ct < 8; ++ct)
#pragma unroll
        for (int r = 0; r < 4; ++r)
            xs[(wv * 16 + lq * 4 + r) * GP + ct * 16 + lr] = f2bs(acc[ct][r]);
    __syncthreads();

    int c0 = (l & 7) * 16;
    float asv[16], adv[16];
#pragma unroll
    for (int c = 0; c < 16; ++c) {
        asv[c] = ldf(att_src, c0 + c, bf);
        adv[c] = ldf(att_dst, c0 + c, bf);
    }
#pragma unroll
    for (int p = 0; p < 2; ++p) {
        int rrow = p * 8 + (l >> 3);
        int gn = m0 + rrow;
        const short* srcp = &xs[(wv * 16 + rrow) * GP + c0];
        short8v v0 = *(const short8v*)srcp;
        short8v v1 = *(const short8v*)(srcp + 8);
        if (gn < N) {
            unsigned short* dst = (unsigned short*)h1b + (size_t)gn * 128 + c0;
            *(short8v*)dst = v0;
            *(short8v*)(dst + 8) = v1;
        }
        float ds = 0.f, dd = 0.f;
#pragma unroll
        for (int c = 0; c < 8; ++c) {
            float fv = bs2f((unsigned short)v0[c]);
            ds += fv * asv[c]; dd += fv * adv[c];
        }
#pragma unroll
        for (int c = 0; c < 8; ++c) {
            float fv = bs2f((unsigned short)v1[c]);
            ds += fv * asv[8 + c]; dd += fv * adv[8 + c];
        }
        ds += __shfl_xor(ds, 1, 64);
        dd += __shfl_xor(dd, 1, 64);
        if (gn < N && ((l & 1) == 0)) {
            int h = (l & 7) >> 1;
            a_s[(size_t)gn * 4 + h] = ds;
            a_d[(size_t)gn * 4 + h] = dd;
        }
    }
}

// ---------------------------------------------------------------------------
// K3: blocks reserve contiguous per-bucket ranges, append packed edges
// (src in bits [0,24), dst-local in bits [24,32)).
// ---------------------------------------------------------------------------
__global__ void __launch_bounds__(256)
k_bbin_scatter(const int* __restrict__ ei, const int* __restrict__ flags,
               int* __restrict__ bcur, unsigned* __restrict__ ebuf,
               int E, int N, int nbuck)
{
    __shared__ int hist[512];
    __shared__ int base[512];
    int t = threadIdx.x;
    for (int j = t; j < nbuck; j += 256) hist[j] = 0;
    __syncthreads();
    int f = flags[0];
    int beg = blockIdx.x * EPB, end = min(E, beg + EPB);
    for (int i = beg + t; i < end; i += 256)
        atomicAdd(&hist[ld_dst(ei, i, E, f, N) >> SB], 1);
    __syncthreads();
    for (int j = t; j < nbuck; j += 256) {
        base[j] = hist[j] ? atomicAdd(&bcur[j], hist[j]) : 0;
        hist[j] = 0;
    }
    __syncthreads();
    for (int i = beg + t; i < end; i += 256) {
        int d = ld_dst(ei, i, E, f, N);
        int s = ld_src(ei, i, E, f, N);
        int b = d >> SB;
        int idx = base[b] + atomicAdd(&hist[b], 1);
        ebuf[idx] = (unsigned)s | ((unsigned)(d & ((1 << SB) - 1)) << 24);
    }
}

// ---------------------------------------------------------------------------
// K4: one block per bucket -> node-level CSR offsets + adj.
// ---------------------------------------------------------------------------
__global__ void __launch_bounds__(256)
k_bucket_csr(const unsigned* __restrict__ ebuf, const int* __restrict__ bofs,
             int* __restrict__ offsets, int* __restrict__ adj, int N)
{
    const int npb = 1 << SB;
    __shared__ int hist[npb];
    __shared__ int psum[256];
    int b = blockIdx.x, t = threadIdx.x;
    int n0 = b << SB;
    int ebeg = bofs[b], eend = bofs[b + 1];

    hist[t] = 0;
    __syncthreads();
    for (int i = ebeg + t; i < eend; i += 256)
        atomicAdd(&hist[ebuf[i] >> 24], 1);
    __syncthreads();
    int c = hist[t];
    psum[t] = c;
    __syncthreads();
    for (int st = 1; st < 256; st <<= 1) {
        int add = (t >= st) ? psum[t - st] : 0;
        __syncthreads();
        psum[t] += add;
        __syncthreads();
    }
    int run = ebeg + psum[t] - c;
    int node = n0 + t;
    hist[t] = run;
    if (node < N) offsets[node] = run;
    __syncthreads();
    for (int i = ebeg + t; i < eend; i += 256) {
        unsigned e = ebuf[i];
        int pos = atomicAdd(&hist[e >> 24], 1);
        adj[pos] = (int)(e & 0xFFFFFFu);
    }
}

// ---------------------------------------------------------------------------
// K5: layer-1 softmax-aggregate, 16-lane groups (4 nodes per wave; lane owns
// 8 cols of head l>>2 via one uint4 = full 256B row per group). Packed
// dword->2xfloat unpack + float2 accumulators (v_pk_fma). Unroll-4.
// ---------------------------------------------------------------------------
__device__ __forceinline__ void acc8(float2v& p0, float2v& p1, float2v& p2,
                                     float2v& p3, uint4 q, float w)
{
    float2v wv = {w, w};
    float2v v;
    v[0] = ubits(q.x << 16); v[1] = ubits(q.x & 0xFFFF0000u); p0 += wv * v;
    v[0] = ubits(q.y << 16); v[1] = ubits(q.y & 0xFFFF0000u); p1 += wv * v;
    v[0] = ubits(q.z << 16); v[1] = ubits(q.z & 0xFFFF0000u); p2 += wv * v;
    v[0] = ubits(q.w << 16); v[1] = ubits(q.w & 0xFFFF0000u); p3 += wv * v;
}

__global__ void __launch_bounds__(256)
k_hagg16(const bf16* __restrict__ h1b, const float* __restrict__ a_s,
         const float* __restrict__ a_d, const int* __restrict__ offsets,
         const int* __restrict__ adj, const void* __restrict__ b1,
         const void* __restrict__ W2, const int* __restrict__ flags,
         float* __restrict__ h2, int N)
{
    int bf = flags[1];
    int t = threadIdx.x;
    int g = t >> 4, l = t & 15;
    int n = blockIdx.x * 16 + g;
    if (n >= N) return;
    int h = l >> 2;
    int c0 = l * 8;                       // 8 cols per lane
    const unsigned* h1q = (const unsigned*)h1b;   // 64 dwords per row
    size_t rowsh = 6;                     // row stride = 64 dwords

    int beg = offsets[n], deg = offsets[n + 1] - beg;
    float adh = a_d[(size_t)n * 4 + h];

    float2v p0 = {0.f,0.f}, p1 = {0.f,0.f}, p2 = {0.f,0.f}, p3 = {0.f,0.f};
    float den;
    {   // self loop
        float w = __expf(lrelu(a_s[(size_t)n * 4 + h] + adh));
        uint4 q = *(const uint4*)(h1q + ((size_t)n << rowsh) + l * 4);
        acc8(p0, p1, p2, p3, q, w);
        den = w;
    }
    int i = 0;
    for (; i + 4 <= deg; i += 4) {
        int s0 = adj[beg + i];
        int s1 = adj[beg + i + 1];
        int s2 = adj[beg + i + 2];
        int s3 = adj[beg + i + 3];
        float w0 = __expf(lrelu(a_s[(size_t)s0 * 4 + h] + adh));
        float w1 = __expf(lrelu(a_s[(size_t)s1 * 4 + h] + adh));
        float w2 = __expf(lrelu(a_s[(size_t)s2 * 4 + h] + adh));
        float w3 = __expf(lrelu(a_s[(size_t)s3 * 4 + h] + adh));
        uint4 q0 = *(const uint4*)(h1q + ((size_t)s0 << rowsh) + l * 4);
        uint4 q1 = *(const uint4*)(h1q + ((size_t)s1 << rowsh) + l * 4);
        uint4 q2 = *(const uint4*)(h1q + ((size_t)s2 << rowsh) + l * 4);
        uint4 q3 = *(const uint4*)(h1q + ((size_t)s3 << rowsh) + l * 4);
        den += (w0 + w1) + (w2 + w3);
        acc8(p0, p1, p2, p3, q0, w0);
        acc8(p0, p1, p2, p3, q1, w1);
        acc8(p0, p1, p2, p3, q2, w2);
        acc8(p0, p1, p2, p3, q3, w3);
    }
    for (; i < deg; ++i) {
        int s0 = adj[beg + i];
        float w0 = __expf(lrelu(a_s[(size_t)s0 * 4 + h] + adh));
        uint4 q0 = *(const uint4*)(h1q + ((size_t)s0 << rowsh) + l * 4);
        den += w0;
        acc8(p0, p1, p2, p3, q0, w0);
    }

    float inv = 1.f / (den + 1e-16f);
    float o[8] = { p0[0], p0[1], p1[0], p1[1], p2[0], p2[1], p3[0], p3[1] };
    float p = 0.f;
#pragma unroll
    for (int c = 0; c < 8; ++c) {
        float ov = fmaxf(o[c] * inv + ldf(b1, c0 + c, bf), 0.f);
        p += ov * ldf(W2, c0 + c, bf);
    }
    p += __shfl_xor(p, 1, 64);
    p += __shfl_xor(p, 2, 64);
    p += __shfl_xor(p, 4, 64);
    p += __shfl_xor(p, 8, 64);
    if (l == 0) h2[n] = p;
}

// ---------------------------------------------------------------------------
// K6: layer-2 scalar softmax-aggregate, single pass. 16 lanes per node.
// ---------------------------------------------------------------------------
__global__ void k_agg2(const float* __restrict__ h2, const int* __restrict__ offsets,
                       const int* __restrict__ adj, const void* __restrict__ att_src2,
                       const void* __restrict__ att_dst2, const void* __restrict__ bias2,
                       const int* __restrict__ flags, void* __restrict__ out, int N)
{
    int bf = flags[1];
    int g = (blockIdx.x * blockDim.x + threadIdx.x) >> 4;
    int lane = threadIdx.x & 15;
    if (g >= N) return;
    int n = g;
    float as2 = ldf(att_src2, 0, bf), ad2 = ldf(att_dst2, 0, bf);
    int beg = offsets[n], end = offsets[n + 1], deg = end - beg;
    float hn = h2[n];
    float dterm = hn * ad2;

    float acc = 0.f, den = 0.f;
    if (lane == 0) {
        float ex = __expf(lrelu(hn * as2 + dterm));
        acc = ex * hn; den = ex;
    }
    for (int i = lane; i < deg; i += 16) {
        int s = adj[beg + i];
        float hs = h2[s];
        float ex = __expf(lrelu(hs * as2 + dterm));
        acc += ex * hs; den += ex;
    }
    for (int m = 1; m < 16; m <<= 1) {
        acc += __shfl_xor(acc, m, 64);
        den += __shfl_xor(den, m, 64);
    }
    if (lane == 0) {
        float r = acc / (den + 1e-16f) + ldf(bias2, 0, bf);
        if (bf) ((bf16*)out)[n] = __float2bfloat16(r);
        else    ((float*)out)[n] = r;
    }
}

// ---------------------------------------------------------------------------
extern "C" void kernel_launch(void* const* d_in, const int* in_sizes, int n_in,
                              void* d_out, int out_size, void* d_ws, size_t ws_size,
                              hipStream_t stream)
{
    const void* x        = d_in[0];
    const int*  ei       = (const int*)d_in[1];
    const void* W1       = d_in[2];
    const void* att_src1 = d_in[3];
    const void* att_dst1 = d_in[4];
    const void* b1       = d_in[5];
    const void* W2       = d_in[6];
    const void* att_src2 = d_in[7];
    const void* att_dst2 = d_in[8];
    const void* bias2    = d_in[9];

    int N = in_sizes[0] / 128;
    int E = in_sizes[1] / 2;
    int nbuck = ((N - 1) >> SB) + 1;   // 391 @ N=100k (<= 512)

    char* ws = (char*)d_ws;
    size_t off = 0;
    auto alloc = [&](size_t bytes) -> void* {
        void* p = ws + off;
        off = (off + bytes + 255) & ~(size_t)255;
        return p;
    };
    int*      flags   = (int*)alloc(256);
    float*    a_s     = (float*)alloc((size_t)N * 4 * sizeof(float));
    float*    a_d     = (float*)alloc((size_t)N * 4 * sizeof(float));
    float*    h2      = (float*)alloc((size_t)N * sizeof(float));
    int*      offsets = (int*)alloc((size_t)(N + 1) * sizeof(int));
    int*      adj     = (int*)alloc((size_t)E * sizeof(int));
    unsigned* ebuf    = (unsigned*)alloc((size_t)E * sizeof(unsigned));
    int*      bcnt    = (int*)alloc(1024 * sizeof(int));
    int*      bofs    = (int*)alloc(1028 * sizeof(int));
    int*      bcur    = (int*)alloc(1024 * sizeof(int));
    short*    w1frag  = (short*)alloc(16384 * sizeof(short));
    bf16*     h1b     = (bf16*)alloc((size_t)N * 128 * sizeof(bf16));

    int ebl = (E + EPB - 1) / EPB;

    k_detect<<<1, 256, 0, stream>>>(ei, (const unsigned*)x, flags, bcnt, nbuck);

    k_prep<<<ebl + 64, 256, 0, stream>>>(ei, W1, flags, bcnt, w1frag,
                                         E, N, nbuck, ebl);

    k_gemm_scan<<<1 + (N + 63) / 64, 256, 0, stream>>>(
        x, w1frag, att_src1, att_dst1, flags, h1b, a_s, a_d,
        bcnt, bofs, bcur, offsets, N, E, nbuck);

    k_bbin_scatter<<<ebl, 256, 0, stream>>>(ei, flags, bcur, ebuf, E, N, nbuck);
    k_bucket_csr<<<nbuck, 256, 0, stream>>>(ebuf, bofs, offsets, adj, N);

    k_hagg16<<<(N + 15) / 16, 256, 0, stream>>>(h1b, a_s, a_d, offsets, adj,
                                                b1, W2, flags, h2, N);

    k_agg2<<<((size_t)N * 16 + 255) / 256, 256, 0, stream>>>(
        h2, offsets, adj, att_src2, att_dst2, bias2, flags, d_out, N);
}

// Round 12
// 283.118 us; speedup vs baseline: 1.0164x; 1.0164x over previous
//
#include <hip/hip_runtime.h>
#include <hip/hip_bf16.h>
#include <math.h>

typedef __hip_bfloat16 bf16;
typedef __attribute__((ext_vector_type(8))) short short8v;
typedef __attribute__((ext_vector_type(4))) float float4v;

__device__ __forceinline__ float b2f(bf16 v) { return __bfloat162float(v); }
__device__ __forceinline__ float bs2f(unsigned short s) {
    unsigned u = ((unsigned)s) << 16;
    float f; __builtin_memcpy(&f, &u, 4); return f;
}
__device__ __forceinline__ short f2bs(float v) {
    bf16 b = __float2bfloat16(v);
    short s; __builtin_memcpy(&s, &b, 2); return s;
}
__device__ __forceinline__ float lrelu(float v) { return fmaxf(v, 0.2f * v); }
__device__ __forceinline__ float ldf(const void* p, size_t i, int bf) {
    return bf ? b2f(((const bf16*)p)[i]) : ((const float*)p)[i];
}
__device__ __forceinline__ int ld_src(const int* ei, int e, int E, int f64, int N) {
    int v = f64 ? (int)(((const long long*)ei)[e]) : ei[e];
    if ((unsigned)v >= (unsigned)N) v = 0;
    return v;
}
__device__ __forceinline__ int ld_dst(const int* ei, int e, int E, int f64, int N) {
    int v = f64 ? (int)(((const long long*)ei)[(size_t)E + e]) : ei[(size_t)E + e];
    if ((unsigned)v >= (unsigned)N) v = 0;
    return v;
}

#define EPB 4096   // edges per block in binning passes
#define SB  8      // bucket shift: 256 nodes per bucket

// ---------------------------------------------------------------------------
// K0: dtype detection + bcnt/done zeroing. flags[0]=int64, flags[1]=bf16.
// ---------------------------------------------------------------------------
__global__ void k_detect(const int* __restrict__ ei, const unsigned* __restrict__ xw,
                         int* __restrict__ flags, int* __restrict__ bcnt,
                         int* __restrict__ done, int nbuck)
{
    __shared__ int s_or[256];
    __shared__ int s_cnt[256];
    int t = threadIdx.x;
    for (int j = t; j < nbuck; j += 256) bcnt[j] = 0;
    if (t == 0) done[0] = 0;
    int any = 0, cnt = 0;
    for (int i = t; i < 4096; i += 256) {
        any |= ei[2 * i + 1];
        unsigned e = (xw[i] >> 7) & 0xFFu;
        cnt += (e >= 100u && e <= 134u) ? 1 : 0;
    }
    s_or[t] = any; s_cnt[t] = cnt;
    __syncthreads();
    for (int s = 128; s > 0; s >>= 1) {
        if (t < s) { s_or[t] |= s_or[t + s]; s_cnt[t] += s_cnt[t + s]; }
        __syncthreads();
    }
    if (t == 0) {
        flags[0] = (s_or[0] == 0) ? 1 : 0;
        flags[1] = (s_cnt[0] > 2048) ? 1 : 0;
    }
}

// ---------------------------------------------------------------------------
// K1: blocks [0,ebl) = bucket histogram (last one also does the bucket scan);
// blocks [ebl,ebl+64) = W1->fragment repack.
// ---------------------------------------------------------------------------
__global__ void __launch_bounds__(256)
k_prep(const int* __restrict__ ei, const void* __restrict__ W1,
       const int* __restrict__ flags, int* __restrict__ bcnt,
       short* __restrict__ w1frag, int* __restrict__ done,
       int* __restrict__ bofs, int* __restrict__ bcur, int* __restrict__ offsets,
       int E, int N, int nbuck, int ebl)
{
    int t = threadIdx.x;
    if (blockIdx.x >= ebl) {   // W1 fragment repack
        int bf = flags[1];
        int idx = (blockIdx.x - ebl) * 256 + t;
        if (idx < 16384) {
            int j = idx & 7, l = (idx >> 3) & 63, kk = (idx >> 9) & 3, ct = idx >> 11;
            int k = kk * 32 + (l >> 4) * 8 + j;
            int n = ct * 16 + (l & 15);
            w1frag[idx] = bf ? ((const short*)W1)[k * 128 + n]
                             : f2bs(((const float*)W1)[k * 128 + n]);
        }
        return;
    }
    __shared__ int hist[512];
    for (int j = t; j < nbuck; j += 256) hist[j] = 0;
    __syncthreads();
    int f = flags[0];
    int beg = blockIdx.x * EPB, end = min(E, beg + EPB);
    for (int i = beg + t; i < end; i += 256)
        atomicAdd(&hist[ld_dst(ei, i, E, f, N) >> SB], 1);
    __syncthreads();
    for (int j = t; j < nbuck; j += 256)
        if (hist[j]) atomicAdd(&bcnt[j], hist[j]);

    // last histogram block performs the bucket scan
    __threadfence();
    __shared__ int is_last;
    if (t == 0) is_last = (atomicAdd(done, 1) == ebl - 1) ? 1 : 0;
    __syncthreads();
    if (!is_last) return;
    __threadfence();
    __shared__ int ps[256];
    int i0 = 2 * t, i1 = 2 * t + 1;
    int c0 = (i0 < nbuck) ? bcnt[i0] : 0;
    int c1 = (i1 < nbuck) ? bcnt[i1] : 0;
    int pr = c0 + c1;
    ps[t] = pr;
    __syncthreads();
    for (int s = 1; s < 256; s <<= 1) {
        int add = (t >= s) ? ps[t - s] : 0;
        __syncthreads();
        ps[t] += add;
        __syncthreads();
    }
    int excl = ps[t] - pr;
    if (i0 < nbuck) { bofs[i0] = excl; bcur[i0] = excl; }
    if (i1 < nbuck) { bofs[i1] = excl + c0; bcur[i1] = excl + c0; }
    if (t == 0) { bofs[nbuck] = E; offsets[N] = E; }
}

// ---------------------------------------------------------------------------
// K2: blocks [0,ebl) = edge scatter to buckets (packed src|dlocal<<24);
// blocks >= ebl = MFMA GEMM h1 = x @ W1 + fused a_s/a_d.
// ---------------------------------------------------------------------------
#define GP 136   // LDS row pitch in shorts

__global__ void __launch_bounds__(256)
k_gemm_scatter(const void* __restrict__ x, const short* __restrict__ w1frag,
               const void* __restrict__ att_src, const void* __restrict__ att_dst,
               const int* __restrict__ ei, const int* __restrict__ flags,
               bf16* __restrict__ h1b, float* __restrict__ a_s, float* __restrict__ a_d,
               int* __restrict__ bcur, unsigned* __restrict__ ebuf,
               int N, int E, int nbuck, int ebl)
{
    int t = threadIdx.x;
    if (blockIdx.x < ebl) {    // ---- edge scatter ----
        __shared__ int hist[512];
        __shared__ int base[512];
        for (int j = t; j < nbuck; j += 256) hist[j] = 0;
        __syncthreads();
        int f = flags[0];
        int beg = blockIdx.x * EPB, end = min(E, beg + EPB);
        for (int i = beg + t; i < end; i += 256)
            atomicAdd(&hist[ld_dst(ei, i, E, f, N) >> SB], 1);
        __syncthreads();
        for (int j = t; j < nbuck; j += 256) {
            base[j] = hist[j] ? atomicAdd(&bcur[j], hist[j]) : 0;
            hist[j] = 0;
        }
        __syncthreads();
        for (int i = beg + t; i < end; i += 256) {
            int d = ld_dst(ei, i, E, f, N);
            int s = ld_src(ei, i, E, f, N);
            int b = d >> SB;
            int idx = base[b] + atomicAdd(&hist[b], 1);
            ebuf[idx] = (unsigned)s | ((unsigned)(d & ((1 << SB) - 1)) << 24);
        }
        return;
    }
    // ---- GEMM ----
    __shared__ short xs[64 * GP];
    int bf = flags[1];
    int base = (blockIdx.x - ebl) * 64;
    if (bf) {
        const short8v* xp = (const short8v*)x;
        for (int idx = t; idx < 1024; idx += 256) {
            int m = idx >> 4, v8 = idx & 15;
            int gm = base + m;
            short8v v = (gm < N) ? xp[(size_t)gm * 16 + v8]
                                 : (short8v){0,0,0,0,0,0,0,0};
            *(short8v*)&xs[m * GP + v8 * 8] = v;
        }
    } else {
        const float4* xp = (const float4*)x;
        for (int idx = t; idx < 2048; idx += 256) {
            int m = idx >> 5, v4 = idx & 31;
            int gm = base + m;
            float4 f = (gm < N) ? xp[(size_t)gm * 32 + v4]
                                : make_float4(0.f, 0.f, 0.f, 0.f);
            short* d = &xs[m * GP + v4 * 4];
            d[0] = f2bs(f.x); d[1] = f2bs(f.y); d[2] = f2bs(f.z); d[3] = f2bs(f.w);
        }
    }
    __syncthreads();

    int wv = t >> 6, l = t & 63, lq = l >> 4, lr = l & 15;
    int m0 = base + wv * 16;

    short8v afr[4];
#pragma unroll
    for (int kk = 0; kk < 4; ++kk)
        afr[kk] = *(const short8v*)&xs[(wv * 16 + lr) * GP + kk * 32 + lq * 8];

    float4v acc[8];
#pragma unroll
    for (int ct = 0; ct < 8; ++ct) acc[ct] = (float4v){0.f, 0.f, 0.f, 0.f};

#pragma unroll
    for (int kk = 0; kk < 4; ++kk) {
        short8v a = afr[kk];
#pragma unroll
        for (int ct = 0; ct < 8; ++ct) {
            short8v b = *(const short8v*)(w1frag + (((ct * 4 + kk) * 64 + l) << 3));
            acc[ct] = __builtin_amdgcn_mfma_f32_16x16x32_bf16(a, b, acc[ct], 0, 0, 0);
        }
    }
    __syncthreads();

#pragma unroll
    for (int ct = 0; ct < 8; ++ct)
#pragma unroll
        for (int r = 0; r < 4; ++r)
            xs[(wv * 16 + lq * 4 + r) * GP + ct * 16 + lr] = f2bs(acc[ct][r]);
    __syncthreads();

    int c0 = (l & 7) * 16;
    float asv[16], adv[16];
#pragma unroll
    for (int c = 0; c < 16; ++c) {
        asv[c] = ldf(att_src, c0 + c, bf);
        adv[c] = ldf(att_dst, c0 + c, bf);
    }
#pragma unroll
    for (int p = 0; p < 2; ++p) {
        int rrow = p * 8 + (l >> 3);
        int gn = m0 + rrow;
        const short* srcp = &xs[(wv * 16 + rrow) * GP + c0];
        short8v v0 = *(const short8v*)srcp;
        short8v v1 = *(const short8v*)(srcp + 8);
        if (gn < N) {
            unsigned short* dst = (unsigned short*)h1b + (size_t)gn * 128 + c0;
            *(short8v*)dst = v0;
            *(short8v*)(dst + 8) = v1;
        }
        float ds = 0.f, dd = 0.f;
#pragma unroll
        for (int c = 0; c < 8; ++c) {
            float fv = bs2f((unsigned short)v0[c]);
            ds += fv * asv[c]; dd += fv * adv[c];
        }
#pragma unroll
        for (int c = 0; c < 8; ++c) {
            float fv = bs2f((unsigned short)v1[c]);
            ds += fv * asv[8 + c]; dd += fv * adv[8 + c];
        }
        ds += __shfl_xor(ds, 1, 64);
        dd += __shfl_xor(dd, 1, 64);
        if (gn < N && ((l & 1) == 0)) {
            int h = (l & 7) >> 1;
            a_s[(size_t)gn * 4 + h] = ds;
            a_d[(size_t)gn * 4 + h] = dd;
        }
    }
}

// ---------------------------------------------------------------------------
// K3: one block per bucket -> node-level CSR offsets + adj.
// ---------------------------------------------------------------------------
__global__ void __launch_bounds__(256)
k_bucket_csr(const unsigned* __restrict__ ebuf, const int* __restrict__ bofs,
             int* __restrict__ offsets, int* __restrict__ adj, int N)
{
    const int npb = 1 << SB;
    __shared__ int hist[npb];
    __shared__ int psum[256];
    int b = blockIdx.x, t = threadIdx.x;
    int n0 = b << SB;
    int ebeg = bofs[b], eend = bofs[b + 1];

    hist[t] = 0;
    __syncthreads();
    for (int i = ebeg + t; i < eend; i += 256)
        atomicAdd(&hist[ebuf[i] >> 24], 1);
    __syncthreads();
    int c = hist[t];
    psum[t] = c;
    __syncthreads();
    for (int st = 1; st < 256; st <<= 1) {
        int add = (t >= st) ? psum[t - st] : 0;
        __syncthreads();
        psum[t] += add;
        __syncthreads();
    }
    int run = ebeg + psum[t] - c;
    int node = n0 + t;
    hist[t] = run;
    if (node < N) offsets[node] = run;
    __syncthreads();
    for (int i = ebeg + t; i < eend; i += 256) {
        unsigned e = ebuf[i];
        int pos = atomicAdd(&hist[e >> 24], 1);
        adj[pos] = (int)(e & 0xFFFFFFu);
    }
}

// ---------------------------------------------------------------------------
// K4: layer-1 softmax-aggregate, 32-lane groups (2 nodes/wave; lane owns
// head l>>3, 4 cols via ushort4 = full 256B row per group), unroll-8 with
// batched load issue for MLP. Fused +b1, ReLU, W2 dot -> h2[n].
// ---------------------------------------------------------------------------
__global__ void __launch_bounds__(256)
k_hagg32(const bf16* __restrict__ h1b, const float* __restrict__ a_s,
         const float* __restrict__ a_d, const int* __restrict__ offsets,
         const int* __restrict__ adj, const void* __restrict__ b1,
         const void* __restrict__ W2, const int* __restrict__ flags,
         float* __restrict__ h2, int N)
{
    int bf = flags[1];
    int t = threadIdx.x;
    int g = t >> 5, l = t & 31;
    int n = blockIdx.x * 8 + g;
    if (n >= N) return;
    int h = l >> 3;
    int coff = h * 32 + (l & 7) * 4;

    int beg = offsets[n], deg = offsets[n + 1] - beg;
    float adh = a_d[(size_t)n * 4 + h];
    const unsigned short* h1u = (const unsigned short*)h1b;

    float wself = __expf(lrelu(a_s[(size_t)n * 4 + h] + adh));
    ushort4 u = *(const ushort4*)(h1u + ((size_t)n << 7) + coff);
    float a0 = wself * bs2f(u.x), a1 = wself * bs2f(u.y);
    float a2 = wself * bs2f(u.z), a3 = wself * bs2f(u.w);
    float den = wself;

    int i = 0;
    for (; i + 8 <= deg; i += 8) {
        int sv[8];
#pragma unroll
        for (int j = 0; j < 8; ++j) sv[j] = adj[beg + i + j];
        float wv[8];
#pragma unroll
        for (int j = 0; j < 8; ++j)
            wv[j] = __expf(lrelu(a_s[(size_t)sv[j] * 4 + h] + adh));
        ushort4 vv[8];
#pragma unroll
        for (int j = 0; j < 8; ++j)
            vv[j] = *(const ushort4*)(h1u + ((size_t)sv[j] << 7) + coff);
#pragma unroll
        for (int j = 0; j < 8; ++j) {
            den += wv[j];
            a0 += wv[j] * bs2f(vv[j].x);
            a1 += wv[j] * bs2f(vv[j].y);
            a2 += wv[j] * bs2f(vv[j].z);
            a3 += wv[j] * bs2f(vv[j].w);
        }
    }
    for (; i + 4 <= deg; i += 4) {
        int s0 = adj[beg + i];
        int s1 = adj[beg + i + 1];
        int s2 = adj[beg + i + 2];
        int s3 = adj[beg + i + 3];
        float w0 = __expf(lrelu(a_s[(size_t)s0 * 4 + h] + adh));
        float w1 = __expf(lrelu(a_s[(size_t)s1 * 4 + h] + adh));
        float w2 = __expf(lrelu(a_s[(size_t)s2 * 4 + h] + adh));
        float w3 = __expf(lrelu(a_s[(size_t)s3 * 4 + h] + adh));
        ushort4 v0 = *(const ushort4*)(h1u + ((size_t)s0 << 7) + coff);
        ushort4 v1 = *(const ushort4*)(h1u + ((size_t)s1 << 7) + coff);
        ushort4 v2 = *(const ushort4*)(h1u + ((size_t)s2 << 7) + coff);
        ushort4 v3 = *(const ushort4*)(h1u + ((size_t)s3 << 7) + coff);
        den += (w0 + w1) + (w2 + w3);
        a0 += w0 * bs2f(v0.x) + w1 * bs2f(v1.x) + w2 * bs2f(v2.x) + w3 * bs2f(v3.x);
        a1 += w0 * bs2f(v0.y) + w1 * bs2f(v1.y) + w2 * bs2f(v2.y) + w3 * bs2f(v3.y);
        a2 += w0 * bs2f(v0.z) + w1 * bs2f(v1.z) + w2 * bs2f(v2.z) + w3 * bs2f(v3.z);
        a3 += w0 * bs2f(v0.w) + w1 * bs2f(v1.w) + w2 * bs2f(v2.w) + w3 * bs2f(v3.w);
    }
    for (; i < deg; ++i) {
        int s0 = adj[beg + i];
        float w0 = __expf(lrelu(a_s[(size_t)s0 * 4 + h] + adh));
        ushort4 v0 = *(const ushort4*)(h1u + ((size_t)s0 << 7) + coff);
        den += w0;
        a0 += w0 * bs2f(v0.x);
        a1 += w0 * bs2f(v0.y);
        a2 += w0 * bs2f(v0.z);
        a3 += w0 * bs2f(v0.w);
    }

    float inv = 1.f / (den + 1e-16f);
    float o0 = fmaxf(a0 * inv + ldf(b1, coff + 0, bf), 0.f);
    float o1 = fmaxf(a1 * inv + ldf(b1, coff + 1, bf), 0.f);
    float o2 = fmaxf(a2 * inv + ldf(b1, coff + 2, bf), 0.f);
    float o3 = fmaxf(a3 * inv + ldf(b1, coff + 3, bf), 0.f);

    float p = o0 * ldf(W2, coff + 0, bf) + o1 * ldf(W2, coff + 1, bf)
            + o2 * ldf(W2, coff + 2, bf) + o3 * ldf(W2, coff + 3, bf);
    p += __shfl_xor(p, 1, 64);
    p += __shfl_xor(p, 2, 64);
    p += __shfl_xor(p, 4, 64);
    p += __shfl_xor(p, 8, 64);
    p += __shfl_xor(p, 16, 64);
    if (l == 0) h2[n] = p;
}

// ---------------------------------------------------------------------------
// K5: layer-2 scalar softmax-aggregate, single pass. 16 lanes per node.
// ---------------------------------------------------------------------------
__global__ void k_agg2(const float* __restrict__ h2, const int* __restrict__ offsets,
                       const int* __restrict__ adj, const void* __restrict__ att_src2,
                       const void* __restrict__ att_dst2, const void* __restrict__ bias2,
                       const int* __restrict__ flags, void* __restrict__ out, int N)
{
    int bf = flags[1];
    int g = (blockIdx.x * blockDim.x + threadIdx.x) >> 4;
    int lane = threadIdx.x & 15;
    if (g >= N) return;
    int n = g;
    float as2 = ldf(att_src2, 0, bf), ad2 = ldf(att_dst2, 0, bf);
    int beg = offsets[n], end = offsets[n + 1], deg = end - beg;
    float hn = h2[n];
    float dterm = hn * ad2;

    float acc = 0.f, den = 0.f;
    if (lane == 0) {
        float ex = __expf(lrelu(hn * as2 + dterm));
        acc = ex * hn; den = ex;
    }
    for (int i = lane; i < deg; i += 16) {
        int s = adj[beg + i];
        float hs = h2[s];
        float ex = __expf(lrelu(hs * as2 + dterm));
        acc += ex * hs; den += ex;
    }
    for (int m = 1; m < 16; m <<= 1) {
        acc += __shfl_xor(acc, m, 64);
        den += __shfl_xor(den, m, 64);
    }
    if (lane == 0) {
        float r = acc / (den + 1e-16f) + ldf(bias2, 0, bf);
        if (bf) ((bf16*)out)[n] = __float2bfloat16(r);
        else    ((float*)out)[n] = r;
    }
}

// ---------------------------------------------------------------------------
extern "C" void kernel_launch(void* const* d_in, const int* in_sizes, int n_in,
                              void* d_out, int out_size, void* d_ws, size_t ws_size,
                              hipStream_t stream)
{
    const void* x        = d_in[0];
    const int*  ei       = (const int*)d_in[1];
    const void* W1       = d_in[2];
    const void* att_src1 = d_in[3];
    const void* att_dst1 = d_in[4];
    const void* b1       = d_in[5];
    const void* W2       = d_in[6];
    const void* att_src2 = d_in[7];
    const void* att_dst2 = d_in[8];
    const void* bias2    = d_in[9];

    int N = in_sizes[0] / 128;
    int E = in_sizes[1] / 2;
    int nbuck = ((N - 1) >> SB) + 1;   // 391 @ N=100k (<= 512)

    char* ws = (char*)d_ws;
    size_t off = 0;
    auto alloc = [&](size_t bytes) -> void* {
        void* p = ws + off;
        off = (off + bytes + 255) & ~(size_t)255;
        return p;
    };
    int*      flags   = (int*)alloc(256);
    int*      done    = (int*)alloc(256);
    float*    a_s     = (float*)alloc((size_t)N * 4 * sizeof(float));
    float*    a_d     = (float*)alloc((size_t)N * 4 * sizeof(float));
    float*    h2      = (float*)alloc((size_t)N * sizeof(float));
    int*      offsets = (int*)alloc((size_t)(N + 1) * sizeof(int));
    int*      adj     = (int*)alloc((size_t)E * sizeof(int));
    unsigned* ebuf    = (unsigned*)alloc((size_t)E * sizeof(unsigned));
    int*      bcnt    = (int*)alloc(1024 * sizeof(int));
    int*      bofs    = (int*)alloc(1028 * sizeof(int));
    int*      bcur    = (int*)alloc(1024 * sizeof(int));
    short*    w1frag  = (short*)alloc(16384 * sizeof(short));
    bf16*     h1b     = (bf16*)alloc((size_t)N * 128 * sizeof(bf16));

    int ebl = (E + EPB - 1) / EPB;
    int gblocks = (N + 63) / 64;

    k_detect<<<1, 256, 0, stream>>>(ei, (const unsigned*)x, flags, bcnt, done, nbuck);

    k_prep<<<ebl + 64, 256, 0, stream>>>(ei, W1, flags, bcnt, w1frag, done,
                                         bofs, bcur, offsets, E, N, nbuck, ebl);

    k_gemm_scatter<<<ebl + gblocks, 256, 0, stream>>>(
        x, w1frag, att_src1, att_dst1, ei, flags, h1b, a_s, a_d,
        bcur, ebuf, N, E, nbuck, ebl);

    k_bucket_csr<<<nbuck, 256, 0, stream>>>(ebuf, bofs, offsets, adj, N);

    k_hagg32<<<(N + 7) / 8, 256, 0, stream>>>(h1b, a_s, a_d, offsets, adj,
                                              b1, W2, flags, h2, N);

    k_agg2<<<((size_t)N * 16 + 255) / 256, 256, 0, stream>>>(
        h2, offsets, adj, att_src2, att_dst2, bias2, flags, d_out, N);
}